// Round 1
// 408.997 us; speedup vs baseline: 1.0184x; 1.0184x over previous
//
#include <hip/hip_runtime.h>

#define BB 32
#define TT 4096
#define DD 512
#define HH 8
#define HDD 64
#define SCALE_F 0.125f   // 64^-0.5 exact
#define CHUNKS 16        // chunks per batch (256 rows each) -> grid 512 = 2 blocks/CU, one round
#define TC 256           // rows per chunk
#define RW 64            // rows per wave (4 waves per block)

// ---------------- A: u[b,h,:] = SCALE * Wk_h^T (Wq_h . enc[b,-1,:]) ----------
__global__ __launch_bounds__(256) void k_qu(const float* __restrict__ enc,
                                            const float* __restrict__ Wq,
                                            const float* __restrict__ Wk,
                                            float* __restrict__ u) {
    __shared__ float x[DD];
    __shared__ float qh[HDD];
    int b = blockIdx.x >> 3, h = blockIdx.x & 7;
    int tid = threadIdx.x;
    const float* el = enc + ((size_t)b * TT + (TT - 1)) * DD;
    for (int i = tid; i < DD; i += 256) x[i] = el[i];
    __syncthreads();
    if (tid < HDD) {
        const float4* wr = (const float4*)(Wq + (size_t)(h * HDD + tid) * DD);
        float acc = 0.f;
#pragma unroll 4
        for (int d = 0; d < DD / 4; ++d) {
            float4 w = wr[d];
            acc += w.x * x[4 * d] + w.y * x[4 * d + 1] + w.z * x[4 * d + 2] + w.w * x[4 * d + 3];
        }
        qh[tid] = acc;
    }
    __syncthreads();
#pragma unroll
    for (int k = 0; k < 2; ++k) {
        int d = tid + 256 * k;
        float acc = 0.f;
#pragma unroll 8
        for (int j = 0; j < HDD; ++j)
            acc += qh[j] * Wk[(size_t)(h * HDD + j) * DD + d];
        u[(size_t)(b * HH + h) * DD + d] = acc * SCALE_F;
    }
}

// ---------------- B: wave-autonomous fused scores+exp+wsum ------------------
// No barriers / no LDS in the main loop. Each wave owns 64 rows:
//   per row: 2x float4 global load (2-deep prefetch) -> fold-butterfly dot
//   -> exp -> 8x shfl broadcast -> 64-FMA accumulate into registers.
// LDS only for the end-of-chunk cross-wave reduction (red[4][8][512], 64 KiB).
__global__ __launch_bounds__(256) void k_main(const float* __restrict__ enc,
                                              const float* __restrict__ u,
                                              float* __restrict__ wt,
                                              float* __restrict__ lsum,
                                              float* __restrict__ partial) {
    __shared__ float red[4][HH][DD];   // 64 KiB
    __shared__ float ls[HH];
    int b = blockIdx.x / CHUNKS, c = blockIdx.x % CHUNKS;
    int t0 = c * TC;
    int tid = threadIdx.x, wave = tid >> 6, lane = tid & 63;
    if (tid < HH) ls[tid] = 0.f;
    __syncthreads();

    const float* ub = u + (size_t)b * HH * DD;
    float4 uA[HH], uB[HH];
#pragma unroll
    for (int h = 0; h < HH; ++h) {
        uA[h] = *(const float4*)(ub + h * DD + 4 * lane);
        uB[h] = *(const float4*)(ub + h * DD + 256 + 4 * lane);
    }
    bool b3 = (lane & 8) != 0, b4 = (lane & 16) != 0, b5 = (lane & 32) != 0;
    int myh = ((lane >> 3) & 1) * 4 + ((lane >> 4) & 1) * 2 + ((lane >> 5) & 1);

    float4 accA[HH], accB[HH];
#pragma unroll
    for (int h = 0; h < HH; ++h) {
        accA[h] = make_float4(0.f, 0.f, 0.f, 0.f);
        accB[h] = make_float4(0.f, 0.f, 0.f, 0.f);
    }

    int trow = t0 + wave * RW;
    const float* rp = enc + ((size_t)b * TT + trow) * DD;
    float* wrow = wt + (size_t)(b * HH + myh) * TT + trow;

    // 2-deep register prefetch
    float4 c0 = *(const float4*)(rp + 4 * lane);
    float4 c1 = *(const float4*)(rp + 256 + 4 * lane);
    float4 d0 = *(const float4*)(rp + DD + 4 * lane);
    float4 d1 = *(const float4*)(rp + DD + 256 + 4 * lane);
    float Lacc = 0.f;

    for (int i = 0; i < RW; ++i) {
        float4 e0 = c0, e1 = c1;
        c0 = d0; c1 = d1;
        if (i + 2 < RW) {
            const float* np = rp + (size_t)(i + 2) * DD;
            d0 = *(const float4*)(np + 4 * lane);
            d1 = *(const float4*)(np + 256 + 4 * lane);
        }
        // ---- scores: per-lane partial dots for all 8 heads ----
        float a[HH];
#pragma unroll
        for (int h = 0; h < HH; ++h)
            a[h] = uA[h].x * e0.x + uA[h].y * e0.y + uA[h].z * e0.z + uA[h].w * e0.w
                 + uB[h].x * e1.x + uB[h].y * e1.y + uB[h].z * e1.z + uB[h].w * e1.w;
        // ---- fold butterfly (R3/R5-verified): all lanes end with head myh ----
        float s[4];
#pragma unroll
        for (int j = 0; j < 4; ++j) {
            float snd = b3 ? a[j] : a[j + 4];
            float kp  = b3 ? a[j + 4] : a[j];
            s[j] = kp + __shfl_xor(snd, 8, 64);
        }
        float p[2];
#pragma unroll
        for (int j = 0; j < 2; ++j) {
            float snd = b4 ? s[j] : s[j + 2];
            float kp  = b4 ? s[j + 2] : s[j];
            p[j] = kp + __shfl_xor(snd, 16, 64);
        }
        float snd = b5 ? p[0] : p[1];
        float q0 = (b5 ? p[1] : p[0]) + __shfl_xor(snd, 32, 64);
        q0 += __shfl_xor(q0, 1, 64);
        q0 += __shfl_xor(q0, 2, 64);
        q0 += __shfl_xor(q0, 4, 64);
        float w = __expf(q0);
        Lacc += w;
        if ((lane & 7) == 0) wrow[i] = w;
        // ---- broadcast 8 head weights to all lanes (group of head h lives
        //      at lane ((h&4)?8:0)|((h&2)?16:0)|((h&1)?32:0)) ----
        float wv[HH];
        wv[0] = __shfl(w, 0, 64);
        wv[1] = __shfl(w, 32, 64);
        wv[2] = __shfl(w, 16, 64);
        wv[3] = __shfl(w, 48, 64);
        wv[4] = __shfl(w, 8, 64);
        wv[5] = __shfl(w, 40, 64);
        wv[6] = __shfl(w, 24, 64);
        wv[7] = __shfl(w, 56, 64);
        // ---- weighted-sum accumulate (lane's own 8 columns x 8 heads) ----
#pragma unroll
        for (int h = 0; h < HH; ++h) {
            accA[h].x += wv[h] * e0.x; accA[h].y += wv[h] * e0.y;
            accA[h].z += wv[h] * e0.z; accA[h].w += wv[h] * e0.w;
            accB[h].x += wv[h] * e1.x; accB[h].y += wv[h] * e1.y;
            accB[h].z += wv[h] * e1.z; accB[h].w += wv[h] * e1.w;
        }
    }

    // ---- cross-wave reduction via LDS (one barrier per chunk) ----
#pragma unroll
    for (int h = 0; h < HH; ++h) {
        *(float4*)&red[wave][h][4 * lane] = accA[h];
        *(float4*)&red[wave][h][256 + 4 * lane] = accB[h];
    }
    if ((lane & 7) == 0) atomicAdd(&ls[myh], Lacc);
    __syncthreads();
    {
        int h = tid >> 5, col = (tid & 31) * 4;
        float* pb = partial + ((size_t)(b * CHUNKS + c) * HH + h) * DD;
#pragma unroll
        for (int j = 0; j < 4; ++j) {
            float4 r0 = *(const float4*)&red[0][h][col + 128 * j];
            float4 r1 = *(const float4*)&red[1][h][col + 128 * j];
            float4 r2 = *(const float4*)&red[2][h][col + 128 * j];
            float4 r3 = *(const float4*)&red[3][h][col + 128 * j];
            float4 o = make_float4(r0.x + r1.x + r2.x + r3.x,
                                   r0.y + r1.y + r2.y + r3.y,
                                   r0.z + r1.z + r2.z + r3.z,
                                   r0.w + r1.w + r2.w + r3.w);
            *(float4*)(pb + col + 128 * j) = o;
        }
    }
    if (tid < HH) lsum[(size_t)(b * CHUNKS + c) * HH + tid] = ls[tid];
}

// ---------------- C: ctx reduce + normalize + Wv dot  (grid B*H) -------------
__global__ __launch_bounds__(256) void k_vctx(const float* __restrict__ partial,
                                              const float* __restrict__ lsum,
                                              const float* __restrict__ Wv,
                                              float* __restrict__ ctxv) {
    __shared__ float cs[DD];
    __shared__ float Linv;
    int b = blockIdx.x >> 3, h = blockIdx.x & 7;
    int tid = threadIdx.x;
    if (tid == 0) {
        float L = 0.f;
#pragma unroll 8
        for (int c = 0; c < CHUNKS; ++c) L += lsum[(size_t)(b * CHUNKS + c) * HH + h];
        Linv = 1.0f / L;
    }
    float a0 = 0.f, a1 = 0.f;
    const float* pb = partial + (size_t)(b * CHUNKS) * HH * DD + (size_t)h * DD;
#pragma unroll 8
    for (int c = 0; c < CHUNKS; ++c) {
        const float* pp = pb + (size_t)c * HH * DD;
        a0 += pp[tid]; a1 += pp[tid + 256];
    }
    __syncthreads();
    cs[tid] = a0 * Linv; cs[tid + 256] = a1 * Linv;
    __syncthreads();
    int out = tid >> 2, q = tid & 3;
    int i = h * HDD + out;
    const float4* wr = (const float4*)(Wv + (size_t)i * DD + q * 128);
    const float* cc = cs + q * 128;
    float acc = 0.f;
#pragma unroll 8
    for (int d = 0; d < 32; ++d) {
        float4 w = wr[d];
        acc += w.x * cc[4 * d] + w.y * cc[4 * d + 1] + w.z * cc[4 * d + 2] + w.w * cc[4 * d + 3];
    }
    acc += __shfl_xor(acc, 1, 64);
    acc += __shfl_xor(acc, 2, 64);
    if (q == 0) ctxv[(size_t)b * DD + i] = acc;
}

// ---------------- G2: out0[b, g*64+o] = Wo[g*64+o, :] . ctxv[b,:] ------------
__global__ __launch_bounds__(256) void k_o(const float* __restrict__ ctxv,
                                           const float* __restrict__ Wo,
                                           float* __restrict__ out0) {
    __shared__ float cs[DD];
    int b = blockIdx.x >> 3, g = blockIdx.x & 7;
    int tid = threadIdx.x;
    for (int i = tid; i < DD; i += 256) cs[i] = ctxv[(size_t)b * DD + i];
    __syncthreads();
    int out = tid >> 2, q = tid & 3;
    int o = g * HDD + out;
    const float4* wr = (const float4*)(Wo + (size_t)o * DD + q * 128);
    const float* cc = cs + q * 128;
    float acc = 0.f;
#pragma unroll 8
    for (int d = 0; d < 32; ++d) {
        float4 w = wr[d];
        acc += w.x * cc[4 * d] + w.y * cc[4 * d + 1] + w.z * cc[4 * d + 2] + w.w * cc[4 * d + 3];
    }
    acc += __shfl_xor(acc, 1, 64);
    acc += __shfl_xor(acc, 2, 64);
    if (q == 0) out0[(size_t)b * DD + o] = acc;
}

// ---------------- D: out1[b,t] = (1/8) sum_h wt[b,h,t] / L[b,h] --------------
__global__ __launch_bounds__(256) void k_out1(const float* __restrict__ wt,
                                              const float* __restrict__ lsum,
                                              float* __restrict__ out1) {
    __shared__ float Linv[HH];
    int b = blockIdx.x >> 3, seg = blockIdx.x & 7;
    int tid = threadIdx.x;
    if (tid < HH) {
        float s = 0.f;
#pragma unroll 8
        for (int c = 0; c < CHUNKS; ++c) s += lsum[(size_t)(b * CHUNKS + c) * HH + tid];
        Linv[tid] = 0.125f / s;
    }
    __syncthreads();
#pragma unroll
    for (int k = 0; k < 2; ++k) {
        int t = seg * 512 + tid + 256 * k;
        float s = 0.f;
#pragma unroll
        for (int h = 0; h < HH; ++h)
            s += wt[(size_t)(b * HH + h) * TT + t] * Linv[h];
        out1[(size_t)b * TT + t] = s;
    }
}

extern "C" void kernel_launch(void* const* d_in, const int* in_sizes, int n_in,
                              void* d_out, int out_size, void* d_ws, size_t ws_size,
                              hipStream_t stream) {
    const float* enc = (const float*)d_in[0];
    const float* Wq  = (const float*)d_in[1];
    const float* Wk  = (const float*)d_in[2];
    const float* Wv  = (const float*)d_in[3];
    const float* Wo  = (const float*)d_in[4];

    float* ws = (float*)d_ws;
    float* u       = ws;                                      // B*H*D        = 131072
    float* wt      = u + (size_t)BB * HH * DD;                // B*H*T        = 1048576
    float* lsum    = wt + (size_t)BB * HH * TT;               // B*CHUNKS*H   = 4096
    float* partial = lsum + (size_t)BB * CHUNKS * HH;         // B*CHUNKS*H*D = 2097152
    float* ctxv    = partial + (size_t)BB * CHUNKS * HH * DD; // B*D          = 16384
    // total ~3.3M floats (~13 MB)

    float* out0 = (float*)d_out;          // [B, D]
    float* out1 = out0 + BB * DD;         // [B, T]

    hipLaunchKernelGGL(k_qu,    dim3(BB * HH),     dim3(256), 0, stream, enc, Wq, Wk, u);
    hipLaunchKernelGGL(k_main,  dim3(BB * CHUNKS), dim3(256), 0, stream, enc, u, wt, lsum, partial);
    hipLaunchKernelGGL(k_vctx,  dim3(BB * HH),     dim3(256), 0, stream, partial, lsum, Wv, ctxv);
    hipLaunchKernelGGL(k_o,     dim3(BB * HH),     dim3(256), 0, stream, ctxv, Wo, out0);
    hipLaunchKernelGGL(k_out1,  dim3(BB * HH),     dim3(256), 0, stream, wt, lsum, out1);
}